// Round 1
// baseline (1321.226 us; speedup 1.0000x reference)
//
#include <hip/hip_runtime.h>
#include <math.h>

#define B_ROWS 512
#define E_DIM  512
#define C_COLS 100000

#define S_SCALE 64.0f
#define COS_M   0.87758256189037276f
#define SIN_M   0.47942553860420301f
#define MM_C    0.23971276930210156f   // sin(m)*m
#define TH_C   -0.87758256189037276f   // cos(pi - m)
#define EPS_C   1e-6f

#define BM 128
#define BN 128
#define BK 16
#define LDA_S 132   // padded LDS stride for As (16B-aligned, conflict-free)

// ---------- kernel 1a: partial column sum-of-squares (deterministic, no atomics) ----------
__global__ __launch_bounds__(256) void colnorm_partial(const float* __restrict__ Km,
                                                       float* __restrict__ partial) {
    int c = blockIdx.x * 256 + threadIdx.x;
    int ey = blockIdx.y;                      // 0..3, each covers 128 rows of E
    if (c >= C_COLS) return;
    const float* p = Km + (size_t)ey * 128 * C_COLS + c;
    float s = 0.f;
    #pragma unroll 8
    for (int e = 0; e < 128; ++e) {
        float v = p[(size_t)e * C_COLS];
        s = fmaf(v, v, s);
    }
    partial[ey * C_COLS + c] = s;
}

// ---------- kernel 1b: inv_norm = 1/(sqrt(sum)+eps) ----------
__global__ __launch_bounds__(256) void colnorm_finalize(const float* __restrict__ partial,
                                                        float* __restrict__ inv_norm) {
    int c = blockIdx.x * 256 + threadIdx.x;
    if (c >= C_COLS) return;
    float s = partial[c] + partial[C_COLS + c] + partial[2 * C_COLS + c] + partial[3 * C_COLS + c];
    inv_norm[c] = 1.f / (sqrtf(s) + EPS_C);
}

// ---------- kernel 2: fp32 tiled GEMM + fused ArcFace epilogue ----------
__global__ __launch_bounds__(256) void gemm_arcface(
    const float* __restrict__ A,        // emb [512][512]
    const float* __restrict__ Km,       // kernel [512][C]
    const int*   __restrict__ label,    // [512]
    const float* __restrict__ inv_norm, // [C]
    float* __restrict__ outp,           // [512][C]
    float* __restrict__ cosp)           // [512][C]
{
    __shared__ float As[BK][LDA_S];
    __shared__ float Bs[BK][BN];

    int bid = blockIdx.x;
    int bm = bid & 3;                   // M-tile fast: 4 row-blocks of one B-panel are adjacent (L2 reuse)
    int bn = bid >> 2;
    int t  = threadIdx.x;
    int tx = t & 15, ty = t >> 4;

    int row0 = bm * BM;
    int col0 = bn * BN;

    float acc[8][8];
    #pragma unroll
    for (int i = 0; i < 8; ++i)
        #pragma unroll
        for (int j = 0; j < 8; ++j) acc[i][j] = 0.f;

    for (int kb = 0; kb < E_DIM / BK; ++kb) {
        int k0 = kb * BK;
        // stage A, transposed into As[k][m]
        #pragma unroll
        for (int p = 0; p < 2; ++p) {
            int f = t + p * 256;              // 512 float4 = 128 rows x 4 quads
            int row = f >> 2, q = f & 3;
            const float4 va = *(const float4*)(A + (size_t)(row0 + row) * E_DIM + k0 + q * 4);
            As[q * 4 + 0][row] = va.x;
            As[q * 4 + 1][row] = va.y;
            As[q * 4 + 2][row] = va.z;
            As[q * 4 + 3][row] = va.w;
        }
        // stage B (row-major, no transpose), guard last partial tile
        #pragma unroll
        for (int p = 0; p < 2; ++p) {
            int f = t + p * 256;              // 512 float4 = 16 rows x 32 quads
            int krow = f >> 5, c4 = (f & 31) * 4;
            int col = col0 + c4;
            if (col < C_COLS) {
                const float4 vb = *(const float4*)(Km + (size_t)(k0 + krow) * C_COLS + col);
                *(float4*)&Bs[krow][c4] = vb;
            }
        }
        __syncthreads();
        #pragma unroll
        for (int k = 0; k < BK; ++k) {
            float4 a0 = *(const float4*)&As[k][4 * ty];
            float4 a1 = *(const float4*)&As[k][64 + 4 * ty];
            float4 b0 = *(const float4*)&Bs[k][4 * tx];
            float4 b1 = *(const float4*)&Bs[k][64 + 4 * tx];
            float av[8] = {a0.x, a0.y, a0.z, a0.w, a1.x, a1.y, a1.z, a1.w};
            float bv[8] = {b0.x, b0.y, b0.z, b0.w, b1.x, b1.y, b1.z, b1.w};
            #pragma unroll
            for (int i = 0; i < 8; ++i)
                #pragma unroll
                for (int j = 0; j < 8; ++j)
                    acc[i][j] = fmaf(av[i], bv[j], acc[i][j]);
        }
        __syncthreads();
    }

    // fused ArcFace epilogue
    int lbl[8];
    #pragma unroll
    for (int i = 0; i < 8; ++i) {
        int grow = row0 + ((i < 4) ? (4 * ty + i) : (64 + 4 * ty + (i - 4)));
        lbl[i] = label[grow];
    }
    #pragma unroll
    for (int i = 0; i < 8; ++i) {
        int grow = row0 + ((i < 4) ? (4 * ty + i) : (64 + 4 * ty + (i - 4)));
        size_t base = (size_t)grow * C_COLS;
        #pragma unroll
        for (int j = 0; j < 8; ++j) {
            int col = col0 + ((j < 4) ? (4 * tx + j) : (64 + 4 * tx + (j - 4)));
            if (col < C_COLS) {
                float v    = acc[i][j] * inv_norm[col];
                float cosv = fminf(1.f, fmaxf(-1.f, v));
                float sinv = sqrtf(fmaxf(0.f, 1.f - cosv * cosv));
                float ctm  = cosv * COS_M - sinv * SIN_M;
                if (cosv <= TH_C) ctm = cosv - MM_C;   // easy-margin fallback
                float o = ((col == lbl[i]) ? ctm : cosv) * S_SCALE;
                outp[base + col] = o;
                cosp[base + col] = cosv;
            }
        }
    }
}

// ---------- kernel 3: per-row online logsumexp + row loss term ----------
__global__ __launch_bounds__(256) void lse_loss(const float* __restrict__ outp,
                                                const int* __restrict__ label,
                                                float* __restrict__ rowloss) {
    int row = blockIdx.x;
    int t = threadIdx.x;
    const float* pr = outp + (size_t)row * C_COLS;
    float m = -INFINITY, s = 0.f;
    for (int c = t; c < C_COLS; c += 256) {
        float x = pr[c];
        if (x > m) { s = s * __expf(m - x) + 1.f; m = x; }
        else       { s += __expf(x - m); }
    }
    __shared__ float sm[256], ss[256];
    sm[t] = m; ss[t] = s;
    __syncthreads();
    for (int off = 128; off > 0; off >>= 1) {
        if (t < off) {
            float m2 = sm[t + off], s2 = ss[t + off];
            float M = fmaxf(sm[t], m2);
            ss[t] = ss[t] * __expf(sm[t] - M) + s2 * __expf(m2 - M);
            sm[t] = M;
        }
        __syncthreads();
    }
    if (t == 0) {
        float logZ = sm[0] + logf(ss[0]);
        rowloss[row] = logZ - pr[label[row]];
    }
}

// ---------- kernel 4: mean over rows -> d_out[0] ----------
__global__ __launch_bounds__(256) void loss_reduce(const float* __restrict__ rowloss,
                                                   float* __restrict__ loss) {
    int t = threadIdx.x;
    float s = rowloss[t] + rowloss[t + 256];
    __shared__ float sm[256];
    sm[t] = s;
    __syncthreads();
    for (int off = 128; off > 0; off >>= 1) {
        if (t < off) sm[t] += sm[t + off];
        __syncthreads();
    }
    if (t == 0) loss[0] = sm[0] * (1.f / (float)B_ROWS);
}

extern "C" void kernel_launch(void* const* d_in, const int* in_sizes, int n_in,
                              void* d_out, int out_size, void* d_ws, size_t ws_size,
                              hipStream_t stream) {
    const float* emb   = (const float*)d_in[0];
    const float* Km    = (const float*)d_in[1];
    const int*   label = (const int*)d_in[2];

    float* out  = (float*)d_out;
    float* outp = out + 1;                                  // [512][C]
    float* cosp = outp + (size_t)B_ROWS * C_COLS;           // [512][C]

    float* ws       = (float*)d_ws;
    float* partial  = ws;                                   // 4*C floats
    float* inv_norm = ws + 4 * (size_t)C_COLS;              // C floats
    float* rowloss  = ws + 5 * (size_t)C_COLS;              // B floats

    dim3 g1((C_COLS + 255) / 256, 4);
    colnorm_partial<<<g1, 256, 0, stream>>>(Km, partial);
    colnorm_finalize<<<(C_COLS + 255) / 256, 256, 0, stream>>>(partial, inv_norm);

    int nTilesN = (C_COLS + BN - 1) / BN;                   // 782
    gemm_arcface<<<nTilesN * 4, 256, 0, stream>>>(emb, Km, label, inv_norm, outp, cosp);

    lse_loss<<<B_ROWS, 256, 0, stream>>>(outp, label, rowloss);
    loss_reduce<<<1, 256, 0, stream>>>(rowloss, out);
}

// Round 2
// 683.918 us; speedup vs baseline: 1.9318x; 1.9318x over previous
//
#include <hip/hip_runtime.h>
#include <math.h>

typedef _Float16 half8 __attribute__((ext_vector_type(8)));
typedef _Float16 half4v __attribute__((ext_vector_type(4)));
typedef float f32x4 __attribute__((ext_vector_type(4)));

#define B_ROWS 512
#define E_DIM  512
#define C_COLS 100000

#define S_SCALE 64.0f
#define COS_M   0.87758256189037276f
#define SIN_M   0.47942553860420301f
#define MM_C    0.23971276930210156f   // sin(m)*m
#define TH_C   -0.87758256189037276f   // cos(pi - m)
#define EPS_C   1e-6f
#define L2E     1.4426950408889634f
#define MAXL    64.0f                  // fixed softmax max bound (|logit| <= 64)

#define BM 128
#define BN 128
#define BK 32

// LDS layout (bytes)
#define AS_OFF   0        // A tile: 128 rows x 128B (fp16, 2 K-steps, unit-swizzled)
#define BS_OFF   16384    // B tile: 8 csub x 1040B (fragment-major fp16)
#define LBL_OFF  24704    // 128 labels
#define SMEM_SZ  25216

// ---------- kernel 0: emb fp32 -> fp16 (RNE), layout [m][8 segpair][8 units x 16B], unit XOR-swizzled ----------
__global__ __launch_bounds__(256) void emb_prep(const float* __restrict__ emb,
                                                uint4* __restrict__ embh) {
    int tid = blockIdx.x * 256 + threadIdx.x;       // 4096 tasks
    int m = tid >> 3, sp = tid & 7;
    const float* src = emb + (size_t)m * E_DIM + sp * 64;
    float x[64];
    #pragma unroll
    for (int q = 0; q < 16; ++q) {
        float4 v = *(const float4*)(src + q * 4);
        x[q * 4 + 0] = v.x; x[q * 4 + 1] = v.y; x[q * 4 + 2] = v.z; x[q * 4 + 3] = v.w;
    }
    #pragma unroll
    for (int u = 0; u < 8; ++u) {
        half8 h;
        #pragma unroll
        for (int j = 0; j < 8; ++j) h[j] = (_Float16)x[u * 8 + j];
        embh[(size_t)m * 64 + sp * 8 + (u ^ (m & 7))] = __builtin_bit_cast(uint4, h);
    }
}

// ---------- kernel 1: fp16 MFMA GEMM + fused colnorm + ArcFace + softmax partials ----------
__global__ __launch_bounds__(256, 2) void gemm_arcface(
    const float* __restrict__ Km,        // [512][C] fp32
    const uint4* __restrict__ embh,      // prepped fp16 A
    const int*   __restrict__ label,
    float* __restrict__ outp, float* __restrict__ cosp,
    float* __restrict__ rowsum)
{
    __shared__ __align__(128) char smem[SMEM_SZ];

    // XCD-chunk swizzle: 3128 = 8 * 391 (bijective)
    int swz = (blockIdx.x & 7) * 391 + (blockIdx.x >> 3);
    int bm = swz & 3, bn = swz >> 2;
    int m0 = bm * BM, col0 = bn * BN;

    int t = threadIdx.x;
    int lane = t & 63, wid = t >> 6;
    int wm = wid >> 1, wc = wid & 1;     // 2x2 wave grid, 64x64 per wave

    // stage labels once
    if (t < 128) *(int*)(smem + LBL_OFF + t * 4) = label[m0 + t];

    f32x4 acc[4][4];
    #pragma unroll
    for (int i = 0; i < 4; ++i)
        #pragma unroll
        for (int j = 0; j < 4; ++j) acc[i][j] = (f32x4){0.f, 0.f, 0.f, 0.f};

    // B staging thread mapping: cq = t&31 (4 cols), kq = t>>5 (4 k-rows)
    int cq = t & 31, kq = t >> 5;
    int myc = col0 + cq * 4;
    bool cok = (myc < C_COLS);           // C%4==0 -> whole quad valid or not
    float sq[4] = {0.f, 0.f, 0.f, 0.f};  // col sumsq partials (fp32, pre-conversion)

    for (int kb = 0; kb < E_DIM / BK; ++kb) {
        // ---- stage A (every other step: 2 K-steps per 16KB tile), verbatim copy ----
        if ((kb & 1) == 0) {
            int sp = kb >> 1;
            #pragma unroll
            for (int p = 0; p < 4; ++p) {
                int flat = t + p * 256;           // 1024 units of 16B
                int m_l = flat >> 3, u = flat & 7;
                uint4 v = embh[(size_t)(m0 + m_l) * 64 + sp * 8 + u];
                *(uint4*)(smem + AS_OFF + m_l * 128 + u * 16) = v;
            }
        }
        // ---- stage B: fp32 -> fp16 RNE, fragment-major LDS, fused sumsq ----
        {
            int k0 = kb * BK;
            const float* bp = Km + (size_t)(k0 + kq * 4) * C_COLS + myc;
            float4 r[4];
            #pragma unroll
            for (int j = 0; j < 4; ++j) {
                if (cok) r[j] = *(const float4*)(bp + (size_t)j * C_COLS);
                else     r[j] = (float4){0.f, 0.f, 0.f, 0.f};
            }
            #pragma unroll
            for (int j = 0; j < 4; ++j) {
                sq[0] = fmaf(r[j].x, r[j].x, sq[0]);
                sq[1] = fmaf(r[j].y, r[j].y, sq[1]);
                sq[2] = fmaf(r[j].z, r[j].z, sq[2]);
                sq[3] = fmaf(r[j].w, r[j].w, sq[3]);
            }
            // element (k = kq*4+j, c = cq*4+i) -> csub=cq>>2, g=kq>>1, c16=(cq&3)*4+i, jj=(kq&1)*4+j
            int base = BS_OFF + (cq >> 2) * 1040 + (kq >> 1) * 256 + (kq & 1) * 8;
            #pragma unroll
            for (int i = 0; i < 4; ++i) {
                float e0 = (i == 0) ? r[0].x : (i == 1) ? r[0].y : (i == 2) ? r[0].z : r[0].w;
                float e1 = (i == 0) ? r[1].x : (i == 1) ? r[1].y : (i == 2) ? r[1].z : r[1].w;
                float e2 = (i == 0) ? r[2].x : (i == 1) ? r[2].y : (i == 2) ? r[2].z : r[2].w;
                float e3 = (i == 0) ? r[3].x : (i == 1) ? r[3].y : (i == 2) ? r[3].z : r[3].w;
                half4v hv;
                hv[0] = (_Float16)e0; hv[1] = (_Float16)e1; hv[2] = (_Float16)e2; hv[3] = (_Float16)e3;
                *(half4v*)(smem + base + ((cq & 3) * 4 + i) * 16) = hv;
            }
        }
        __syncthreads();

        // ---- fragments + MFMA ----
        int ubase = (kb & 1) * 4 + (lane >> 4);
        half8 af[4], bf[4];
        #pragma unroll
        for (int mf = 0; mf < 4; ++mf) {
            int m_l = wm * 64 + mf * 16 + (lane & 15);
            af[mf] = __builtin_bit_cast(half8,
                *(const uint4*)(smem + AS_OFF + m_l * 128 + ((ubase ^ (m_l & 7)) << 4)));
        }
        #pragma unroll
        for (int nf = 0; nf < 4; ++nf) {
            int csub = wc * 4 + nf;
            bf[nf] = __builtin_bit_cast(half8,
                *(const uint4*)(smem + BS_OFF + csub * 1040 + (lane >> 4) * 256 + (lane & 15) * 16));
        }
        #pragma unroll
        for (int mf = 0; mf < 4; ++mf)
            #pragma unroll
            for (int nf = 0; nf < 4; ++nf)
                acc[mf][nf] = __builtin_amdgcn_mfma_f32_16x16x32_f16(af[mf], bf[nf], acc[mf][nf], 0, 0, 0);
        __syncthreads();
    }

    // ---- column inv_norm from fused sumsq (reuse As region) ----
    float* sqred = (float*)smem;               // [8][128]
    float* invn  = (float*)(smem + 4096);      // [128]
    #pragma unroll
    for (int i = 0; i < 4; ++i) sqred[kq * 128 + cq * 4 + i] = sq[i];
    __syncthreads();
    if (t < 128) {
        float s = 0.f;
        #pragma unroll
        for (int r = 0; r < 8; ++r) s += sqred[r * 128 + t];
        invn[t] = 1.f / (sqrtf(s) + EPS_C);
    }
    __syncthreads();

    // ---- epilogue: scale, clamp, store, softmax partials ----
    const int* lbls = (const int*)(smem + LBL_OFF);
    float inv4[4];
    #pragma unroll
    for (int nf = 0; nf < 4; ++nf) inv4[nf] = invn[wc * 64 + nf * 16 + (lane & 15)];
    int cbase = col0 + wc * 64 + (lane & 15);

    #pragma unroll
    for (int mf = 0; mf < 4; ++mf) {
        float rsum[4] = {0.f, 0.f, 0.f, 0.f};
        int rl0 = wm * 64 + mf * 16 + (lane >> 4) * 4;
        int lblr[4];
        #pragma unroll
        for (int r = 0; r < 4; ++r) lblr[r] = lbls[rl0 + r];
        #pragma unroll
        for (int nf = 0; nf < 4; ++nf) {
            int c = cbase + nf * 16;
            if (c < C_COLS) {
                f32x4 a = acc[mf][nf];
                #pragma unroll
                for (int r = 0; r < 4; ++r) {
                    float v = a[r] * inv4[nf];
                    v = fminf(1.f, fmaxf(-1.f, v));
                    float o = v * S_SCALE;
                    size_t off = (size_t)(m0 + rl0 + r) * C_COLS + c;
                    outp[off] = o;
                    cosp[off] = v;
                    // label col excluded here; fixup kernel adds its exact term
                    float p = (c == lblr[r]) ? 0.f : exp2f(fmaf(o, L2E, -MAXL * L2E));
                    rsum[r] += p;
                }
            }
        }
        #pragma unroll
        for (int r = 0; r < 4; ++r) {
            float v = rsum[r];
            v += __shfl_xor(v, 1); v += __shfl_xor(v, 2);
            v += __shfl_xor(v, 4); v += __shfl_xor(v, 8);
            if ((lane & 15) == 0) atomicAdd(&rowsum[m0 + rl0 + r], v);
        }
    }
}

// ---------- kernel 2: exact fp32 label-column fixup ----------
__global__ __launch_bounds__(64) void label_fixup(const float* __restrict__ emb,
                                                  const float* __restrict__ Km,
                                                  const int* __restrict__ label,
                                                  float* __restrict__ outp, float* __restrict__ cosp,
                                                  float* __restrict__ rowsum, float* __restrict__ rowtarget) {
    int m = blockIdx.x;
    int l = label[m];
    int t = threadIdx.x;
    float dot = 0.f, ss = 0.f;
    for (int k = t; k < E_DIM; k += 64) {
        float e = emb[(size_t)m * E_DIM + k];
        float w = Km[(size_t)k * C_COLS + l];
        dot = fmaf(e, w, dot);
        ss  = fmaf(w, w, ss);
    }
    #pragma unroll
    for (int s = 1; s < 64; s <<= 1) {
        dot += __shfl_xor(dot, s);
        ss  += __shfl_xor(ss, s);
    }
    if (t == 0) {
        float inv = 1.f / (sqrtf(ss) + EPS_C);
        float c = dot * inv;
        c = fminf(1.f, fmaxf(-1.f, c));
        float sn = sqrtf(fmaxf(0.f, 1.f - c * c));
        float ctm = c * COS_M - sn * SIN_M;
        if (c <= TH_C) ctm = c - MM_C;
        float o = ctm * S_SCALE;
        size_t off = (size_t)m * C_COLS + l;
        outp[off] = o;
        cosp[off] = c;
        rowtarget[m] = o;
        atomicAdd(&rowsum[m], exp2f((o - MAXL) * L2E));
    }
}

// ---------- kernel 3: loss = mean(64 + log(rowsum) - rowtarget) ----------
__global__ __launch_bounds__(512) void final_loss(const float* __restrict__ rowsum,
                                                  const float* __restrict__ rowtarget,
                                                  float* __restrict__ loss) {
    int t = threadIdx.x;
    __shared__ float sm[512];
    sm[t] = MAXL + logf(rowsum[t]) - rowtarget[t];
    __syncthreads();
    for (int off = 256; off > 0; off >>= 1) {
        if (t < off) sm[t] += sm[t + off];
        __syncthreads();
    }
    if (t == 0) loss[0] = sm[0] * (1.f / (float)B_ROWS);
}

extern "C" void kernel_launch(void* const* d_in, const int* in_sizes, int n_in,
                              void* d_out, int out_size, void* d_ws, size_t ws_size,
                              hipStream_t stream) {
    const float* emb   = (const float*)d_in[0];
    const float* Km    = (const float*)d_in[1];
    const int*   label = (const int*)d_in[2];

    float* out  = (float*)d_out;
    float* outp = out + 1;
    float* cosp = outp + (size_t)B_ROWS * C_COLS;

    char* ws = (char*)d_ws;
    uint4* embh      = (uint4*)ws;                       // 512 KB
    float* rowsum    = (float*)(ws + 524288);            // 2 KB
    float* rowtarget = (float*)(ws + 524288 + 2048);     // 2 KB

    emb_prep<<<16, 256, 0, stream>>>(emb, embh);
    hipMemsetAsync(rowsum, 0, B_ROWS * sizeof(float), stream);

    int nTilesN = (C_COLS + BN - 1) / BN;                // 782
    gemm_arcface<<<nTilesN * 4, 256, 0, stream>>>(Km, embh, label, outp, cosp, rowsum);

    label_fixup<<<B_ROWS, 64, 0, stream>>>(emb, Km, label, outp, cosp, rowsum, rowtarget);
    final_loss<<<1, 512, 0, stream>>>(rowsum, rowtarget, out);
}